// Round 6
// baseline (120.091 us; speedup 1.0000x reference)
//
#include <hip/hip_runtime.h>
#include <math.h>

#define VOCABN 100000
#define EMBD 300
#define HID 128
#define NQ 32
#define NTOP 10

#define KPAD 320            // padded K: 20 chunks of 16
#define WK 16
#define NCH 20
#define SC_ROWS 128         // rows per block (4 waves x 32 rows)
#define SC_NBLK ((VOCABN + SC_ROWS - 1) / SC_ROWS)   // 782
#define ESLOTS 640          // 128 rows * 5 slots of 16B (slot 4 = pad/dup)
#define EISSUE 10           // 640 slots / 64 lanes

typedef __attribute__((ext_vector_type(8))) short bf16x8;
typedef __attribute__((ext_vector_type(4))) float f32x4;
typedef __attribute__((ext_vector_type(16))) float f32x16;
typedef __attribute__((ext_vector_type(4))) unsigned int u32x4;

__device__ __forceinline__ void split8(const f32x4 a, const f32x4 b,
                                       u32x4* hi, u32x4* lo) {
    float ef[8] = {a.x, a.y, a.z, a.w, b.x, b.y, b.z, b.w};
    unsigned int hw[8], lw[8];
#pragma unroll
    for (int j = 0; j < 8; ++j) {
        unsigned int u = __float_as_uint(ef[j]);
        hw[j] = u >> 16;
        float r = __uint_as_float(u & 0xffff0000u);
        lw[j] = __float_as_uint(ef[j] - r) >> 16;
    }
    *hi = (u32x4){hw[0] | (hw[1] << 16), hw[2] | (hw[3] << 16),
                  hw[4] | (hw[5] << 16), hw[6] | (hw[7] << 16)};
    *lo = (u32x4){lw[0] | (lw[1] << 16), lw[2] | (lw[3] << 16),
                  lw[4] | (lw[5] << 16), lw[6] | (lw[7] << 16)};
}

// ---------------- fused: histogram | qctx+qcb | W1a transpose+bf16-split ----------------
__global__ __launch_bounds__(256) void k_pre(const int* __restrict__ qterms,
                                             const int* __restrict__ fdocs, int nflat, int hblocks,
                                             const float* __restrict__ emb,
                                             const float* __restrict__ sW1,
                                             const float* __restrict__ sb1,
                                             int* __restrict__ counts,
                                             float* __restrict__ qctx,
                                             float* __restrict__ qcb,
                                             unsigned short* __restrict__ whi,
                                             unsigned short* __restrict__ wlo) {
    int t = threadIdx.x;
    int b = blockIdx.x;
    if (b < hblocks) {                       // histogram
        int i = b * 256 + t;
        if (i < nflat) atomicAdd(&counts[fdocs[i]], 1);
        return;
    }
    if (b == hblocks) {                      // query context + scorer bias
        __shared__ int qid[NQ];
        __shared__ float qc[EMBD];
        if (t < NQ) qid[t] = qterms[t];
        __syncthreads();
        for (int i = t; i < EMBD; i += 256) {
            float s = 0.f;
            for (int q = 0; q < NQ; ++q) s += emb[(long)qid[q] * EMBD + i];
            float v = s * (1.0f / NQ);
            qc[i] = v; qctx[i] = v;
        }
        __syncthreads();
        int col = t >> 1, half = t & 1;
        float a = 0.f;
        int k0 = half * 150;
        for (int k = k0; k < k0 + 150; ++k)
            a += qc[k] * sW1[(long)(EMBD + k) * HID + col];
        a += __shfl_xor(a, 1);
        if (half == 0) qcb[col] = a + sb1[col];
        return;
    }
    // W1a (rows 0..299) -> transposed [col][KPAD], zero-padded, bf16 hi/lo split
    int i = (b - hblocks - 1) * 256 + t;     // over HID*KPAD
    if (i < HID * KPAD) {
        int k = i >> 7, c = i & 127;
        unsigned int hi = 0, lo = 0;
        if (k < EMBD) {
            float f = sW1[(long)k * HID + c];
            unsigned int u = __float_as_uint(f);
            hi = u >> 16;
            float r = __uint_as_float(u & 0xffff0000u);
            lo = __float_as_uint(f - r) >> 16;
        }
        whi[(long)c * KPAD + k] = (unsigned short)hi;
        wlo[(long)c * KPAD + k] = (unsigned short)lo;
    }
}

// ---------------- MFMA 32x32x16 bf16x3 score, all vocab rows, + per-block top-10 ----
// 256 threads (4 waves). Wave w: rows [32w, 32w+32), all 128 cols (4 tiles).
// C/D: col = lane&31, row = (reg&3) + 8*(reg>>2) + 4*(lane>>5)
__global__ __launch_bounds__(256, 4) void k_score(
        const float* __restrict__ emb,
        const unsigned short* __restrict__ whi,
        const unsigned short* __restrict__ wlo,
        const float* __restrict__ qcb,
        const float* __restrict__ sW2,
        const float* __restrict__ sb2,
        const int* __restrict__ counts,
        float* __restrict__ taw, int* __restrict__ tai) {
    __shared__ __align__(16) float Eb[2][ESLOTS * 4];            // 20480 B
    __shared__ __align__(16) unsigned short WH[2][256 * 8];      // 8192 B
    __shared__ __align__(16) unsigned short WL[2][256 * 8];      // 8192 B
    __shared__ float qcb_s[HID], w2_s[HID], wv[SC_ROWS];

    const int tid = threadIdx.x;
    const int blk = blockIdx.x;
    const int base = blk * SC_ROWS;

    if (tid < HID) { qcb_s[tid] = qcb[tid]; w2_s[tid] = sW2[tid]; }

    const int lane = tid & 63;
    const int wave = tid >> 6;       // 0..3
    const int lrow = lane & 31;
    const int khalf = lane >> 5;     // 0..1
    const int wcol = tid >> 1;       // W staging col 0..127
    const int wkh  = tid & 1;        // W staging k-half

    const long FMAX = (long)VOCABN * EMBD - 4;

    f32x16 acc[4];
#pragma unroll
    for (int t = 0; t < 4; ++t)
#pragma unroll
        for (int r = 0; r < 16; ++r) acc[t][r] = 0.f;

    // ---- E staging: slot = i*64+lane; row = slot/5, seg p = slot%5 (p==4 dup) ----
    // consecutive lanes cover one row's 64B window -> coalesced requests
#define E_ISSUE(CHUNK, BUF)                                                          \
    for (int i = wave; i < EISSUE; i += 4) {                                         \
        int slot = i * 64 + lane;                                                    \
        int r_ = slot / 5;                                                           \
        int p_ = slot - r_ * 5; if (p_ > 3) p_ = 0;                                  \
        long vrow = base + r_; if (vrow >= VOCABN) vrow = VOCABN - 1;                \
        long fidx = vrow * EMBD + (CHUNK) * WK + p_ * 4;                             \
        if (fidx > FMAX) fidx = vrow * EMBD;                                         \
        __builtin_amdgcn_global_load_lds(                                            \
            (const __attribute__((address_space(1))) unsigned int*)(emb + fidx),     \
            (__attribute__((address_space(3))) unsigned int*)(&Eb[BUF][i * 256]),    \
            16, 0, 0);                                                               \
    }

    // ---- W staging: fragment-major [kh][tile][col&31] x 16B ----
    u32x4 wh_r, wl_r;
#define W_LOAD(CHUNK)                                                                \
    {                                                                                \
        long o = (long)wcol * KPAD + (CHUNK) * WK + wkh * 8;                         \
        wh_r = *(const u32x4*)&whi[o];                                               \
        wl_r = *(const u32x4*)&wlo[o];                                               \
    }
#define W_STORE(BUF)                                                                 \
    {                                                                                \
        int f = ((wkh * 4 + (wcol >> 5)) * 32 + (wcol & 31)) * 8;                    \
        *(u32x4*)&WH[BUF][f] = wh_r;                                                 \
        *(u32x4*)&WL[BUF][f] = wl_r;                                                 \
    }

    // prologue: chunk 0
    E_ISSUE(0, 0)
    W_LOAD(0)
    W_STORE(0)
    __syncthreads();   // drains E0 (vmcnt) + W0 (lgkm); qcb_s/w2_s ready

    const int erd = (wave * 32 + lrow) * 20 + khalf * 8;   // float offset in Eb

    for (int c = 0; c < NCH; ++c) {
        const int cur = c & 1;
        const bool more = (c + 1 < NCH);
        if (more) {
            E_ISSUE(c + 1, cur ^ 1)
            W_LOAD(c + 1)
        }
        f32x4 e0 = *(const f32x4*)&Eb[cur][erd];
        f32x4 e1 = *(const f32x4*)&Eb[cur][erd + 4];
        union { bf16x8 v; u32x4 u; } eh, el;
        split8(e0, e1, &eh.u, &el.u);
#pragma unroll
        for (int t = 0; t < 4; ++t) {
            union { bf16x8 v; u32x4 u; } bh, bl;
            int f = ((khalf * 4 + t) * 32 + lrow) * 8;
            bh.u = *(const u32x4*)&WH[cur][f];
            bl.u = *(const u32x4*)&WL[cur][f];
            acc[t] = __builtin_amdgcn_mfma_f32_32x32x16_bf16(eh.v, bh.v, acc[t], 0, 0, 0);
            acc[t] = __builtin_amdgcn_mfma_f32_32x32x16_bf16(eh.v, bl.v, acc[t], 0, 0, 0);
            acc[t] = __builtin_amdgcn_mfma_f32_32x32x16_bf16(el.v, bh.v, acc[t], 0, 0, 0);
        }
        if (more) W_STORE(cur ^ 1)
        __syncthreads();
    }

    // epilogue: relu + W2 dot + 32-lane reduce + sigmoid*count
    const float b2 = sb2[0];
    float pr[16];
#pragma unroll
    for (int r = 0; r < 16; ++r) {
        float s = 0.f;
#pragma unroll
        for (int t = 0; t < 4; ++t) {
            int col = t * 32 + lrow;
            float h = fmaxf(acc[t][r] + qcb_s[col], 0.f);
            s += h * w2_s[col];
        }
        s += __shfl_xor(s, 1); s += __shfl_xor(s, 2);
        s += __shfl_xor(s, 4); s += __shfl_xor(s, 8);
        s += __shfl_xor(s, 16);
        pr[r] = s;
    }
    if (lrow == 0) {
#pragma unroll
        for (int r = 0; r < 16; ++r) {
            int row = wave * 32 + (r & 3) + 8 * (r >> 2) + 4 * khalf;
            int v = base + row;
            float wgt = -1.f;
            if (v < VOCABN)
                wgt = (float)counts[v] / (1.f + expf(-(pr[r] + b2)));
            wv[row] = wgt;
        }
    }
    __syncthreads();

    // wave 0: top-10 over the 128 row weights (2 per lane)
    if (tid < 64) {
        float w0 = wv[tid], w1 = wv[tid + 64];
        int i0 = (base + tid < VOCABN) ? base + tid : 0x7fffffff;
        int i1 = (base + tid + 64 < VOCABN) ? base + tid + 64 : 0x7fffffff;
        for (int r = 0; r < NTOP; ++r) {
            float bw; int bid;
            if (w0 > w1 || (w0 == w1 && i0 < i1)) { bw = w0; bid = i0; }
            else                                   { bw = w1; bid = i1; }
            for (int m = 1; m < 64; m <<= 1) {
                float ow = __shfl_xor(bw, m); int oid = __shfl_xor(bid, m);
                if (ow > bw || (ow == bw && oid < bid)) { bw = ow; bid = oid; }
            }
            if (w0 == bw && i0 == bid)      w0 = -2.f;
            else if (w1 == bw && i1 == bid) w1 = -2.f;
            if (tid == r) { taw[blk * NTOP + r] = bw; tai[blk * NTOP + r] = bid; }
        }
    }
}

// ---------------- top-k helpers ----------------
__device__ __forceinline__ bool tbetter(float w1, int i1, float w2, int i2) {
    return w1 > w2 || (w1 == w2 && i1 < i2);
}

__device__ __forceinline__ void lds_insert(float* mw, int* mid, int t, float w, int id) {
    const int b = t * NTOP;
    if (!tbetter(w, id, mw[b + NTOP - 1], mid[b + NTOP - 1])) return;
    int p = NTOP - 1;
    while (p > 0 && tbetter(w, id, mw[b + p - 1], mid[b + p - 1])) {
        mw[b + p] = mw[b + p - 1]; mid[b + p] = mid[b + p - 1]; --p;
    }
    mw[b + p] = w; mid[b + p] = id;
}

// ---------------- final: global top-10 merge + expansion MLP ----------------
__global__ __launch_bounds__(512) void k_final(const float* __restrict__ taw,
                                               const int* __restrict__ tai,
                                               const float* __restrict__ qctx,
                                               const float* __restrict__ emb,
                                               const float* __restrict__ eW1,
                                               const float* __restrict__ eb1,
                                               const float* __restrict__ eW2,
                                               const float* __restrict__ eb2,
                                               float* __restrict__ out) {
    __shared__ float mw[512 * NTOP];   // 20 KB
    __shared__ int   mid[512 * NTOP];  // 20 KB
    __shared__ int   top_id[NTOP];
    __shared__ float qc[EMBD], em[EMBD], hbuf[HID];
    int t = threadIdx.x;
#pragma unroll
    for (int n = 0; n < NTOP; ++n) { mw[t * NTOP + n] = -1.f; mid[t * NTOP + n] = 0x7fffffff; }
    for (int i = t; i < SC_NBLK * NTOP; i += 512)
        lds_insert(mw, mid, t, taw[i], tai[i]);

    for (int s = 256; s > 0; s >>= 1) {
        __syncthreads();
        if (t < s) {
            const int ta = t * NTOP, tb = (t + s) * NTOP;
            float ow[NTOP]; int oid[NTOP];
            int i = 0, j = 0;
#pragma unroll
            for (int n = 0; n < NTOP; ++n) {
                float wa = mw[ta + i]; int ia = mid[ta + i];
                float wb = mw[tb + j]; int ib = mid[tb + j];
                if (tbetter(wa, ia, wb, ib)) { ow[n] = wa; oid[n] = ia; ++i; }
                else                         { ow[n] = wb; oid[n] = ib; ++j; }
            }
#pragma unroll
            for (int n = 0; n < NTOP; ++n) { mw[ta + n] = ow[n]; mid[ta + n] = oid[n]; }
        }
    }
    __syncthreads();

    if (t < NTOP) {
        top_id[t] = mid[t];
        out[EMBD + t] = (float)mid[t];
        out[EMBD + NTOP + t] = mw[t];
    }
    __syncthreads();

    for (int i = t; i < EMBD; i += 512) {
        float s = 0.f;
        for (int n = 0; n < NTOP; ++n) s += emb[(long)top_id[n] * EMBD + i];
        em[i] = s * (1.0f / NTOP);
        qc[i] = qctx[i];
    }
    __syncthreads();

    // h = relu(feat . eW1 + eb1); 4 threads per col, K split 75
    {
        int col = t >> 2, ks = t & 3;
        float a = 0.f;
        int k0 = ks * 75, k1 = k0 + 75;
        for (int k = k0; k < k1; ++k) {
            float q = qc[k], e = em[k];
            a += q * eW1[(long)k * HID + col];
            a += e * eW1[(long)(EMBD + k) * HID + col];
            a += (q * e) * eW1[(long)(2 * EMBD + k) * HID + col];
        }
        a += __shfl_xor(a, 1);
        a += __shfl_xor(a, 2);
        if (ks == 0) hbuf[col] = fmaxf(a + eb1[col], 0.f);
    }
    __syncthreads();

    for (int i = t; i < EMBD; i += 512) {
        float a = eb2[i];
        for (int j = 0; j < HID; ++j) a += hbuf[j] * eW2[(long)j * EMBD + i];
        out[i] = a;
    }
}

extern "C" void kernel_launch(void* const* d_in, const int* in_sizes, int n_in,
                              void* d_out, int out_size, void* d_ws, size_t ws_size,
                              hipStream_t stream) {
    const int* qterms  = (const int*)d_in[0];
    const int* fdocs   = (const int*)d_in[1];
    const float* emb   = (const float*)d_in[3];
    const float* sW1   = (const float*)d_in[4];
    const float* sb1   = (const float*)d_in[5];
    const float* sW2   = (const float*)d_in[6];
    const float* sb2   = (const float*)d_in[7];
    const float* eW1   = (const float*)d_in[8];
    const float* eb1   = (const float*)d_in[9];
    const float* eW2   = (const float*)d_in[10];
    const float* eb2   = (const float*)d_in[11];
    float* out = (float*)d_out;

    char* ws = (char*)d_ws;
    int*   counts = (int*)ws;                             // 400000
    float* qctx   = (float*)(ws + 400000);                // 1200
    float* qcb    = (float*)(ws + 401216);                // 512
    float* taw    = (float*)(ws + 401728);                // 782*10*4 = 31280
    int*   tai    = (int*)(ws + 433008);                  // 31280
    unsigned short* whi = (unsigned short*)(ws + 464288); // 128*320*2 = 81920
    unsigned short* wlo = (unsigned short*)(ws + 546208); // 81920

    int nflat = in_sizes[1];
    int hblocks = (nflat + 255) / 256;
    int wtblocks = (HID * KPAD + 255) / 256;              // 160

    hipMemsetAsync(counts, 0, 400000, stream);
    k_pre<<<hblocks + 1 + wtblocks, 256, 0, stream>>>(qterms, fdocs, nflat, hblocks,
                                                      emb, sW1, sb1, counts, qctx, qcb, whi, wlo);
    k_score<<<SC_NBLK, 256, 0, stream>>>(emb, whi, wlo, qcb, sW2, sb2, counts, taw, tai);
    k_final<<<1, 512, 0, stream>>>(taw, tai, qctx, emb, eW1, eb1, eW2, eb2, out);
}

// Round 7
// 107.290 us; speedup vs baseline: 1.1193x; 1.1193x over previous
//
#include <hip/hip_runtime.h>
#include <math.h>

#define VOCABN 100000
#define EMBD 300
#define HID 128
#define NQ 32
#define NTOP 10

#define NCH 20              // k chunks of 16 (19 real + 1 zero-pad)
#define CMIN 3              // candidate threshold: count >= 3
#define WCAND 43691         // max possible candidates (131072/3)
#define GRID_A ((WCAND + 31) / 32)    // 1366
#define GRID_F ((VOCABN + 31) / 32)   // 3125

typedef __attribute__((ext_vector_type(8))) short bf16x8;
typedef __attribute__((ext_vector_type(4))) float f32x4;
typedef __attribute__((ext_vector_type(16))) float f32x16;
typedef __attribute__((ext_vector_type(4))) unsigned int u32x4;

__device__ __forceinline__ void split8(const f32x4 a, const f32x4 b,
                                       u32x4* hi, u32x4* lo) {
    float ef[8] = {a.x, a.y, a.z, a.w, b.x, b.y, b.z, b.w};
    unsigned int hw[8], lw[8];
#pragma unroll
    for (int j = 0; j < 8; ++j) {
        unsigned int u = __float_as_uint(ef[j]);
        hw[j] = u >> 16;
        float r = __uint_as_float(u & 0xffff0000u);
        lw[j] = __float_as_uint(ef[j] - r) >> 16;
    }
    *hi = (u32x4){hw[0] | (hw[1] << 16), hw[2] | (hw[3] << 16),
                  hw[4] | (hw[5] << 16), hw[6] | (hw[7] << 16)};
    *lo = (u32x4){lw[0] | (lw[1] << 16), lw[2] | (lw[3] << 16),
                  lw[4] | (lw[5] << 16), lw[6] | (lw[7] << 16)};
}

// ---------- fused: histogram | qctx+qcb | W1a -> fragment-major bf16 hi/lo ----------
__global__ __launch_bounds__(256) void k_pre(const int* __restrict__ qterms,
                                             const int* __restrict__ fdocs, int nflat, int hblocks,
                                             const float* __restrict__ emb,
                                             const float* __restrict__ sW1,
                                             const float* __restrict__ sb1,
                                             int* __restrict__ counts,
                                             float* __restrict__ qctx,
                                             float* __restrict__ qcb,
                                             unsigned short* __restrict__ wfH,
                                             unsigned short* __restrict__ wfL) {
    int t = threadIdx.x;
    int b = blockIdx.x;
    if (b < hblocks) {                       // histogram
        int i = b * 256 + t;
        if (i < nflat) atomicAdd(&counts[fdocs[i]], 1);
        return;
    }
    if (b == hblocks) {                      // query context + scorer bias
        __shared__ int qid[NQ];
        __shared__ float qc[EMBD];
        if (t < NQ) qid[t] = qterms[t];
        __syncthreads();
        for (int i = t; i < EMBD; i += 256) {
            float s = 0.f;
            for (int q = 0; q < NQ; ++q) s += emb[(long)qid[q] * EMBD + i];
            float v = s * (1.0f / NQ);
            qc[i] = v; qctx[i] = v;
        }
        __syncthreads();
        int col = t >> 1, half = t & 1;
        float a = 0.f;
        int k0 = half * 150;
        for (int k = k0; k < k0 + 150; ++k)
            a += qc[k] * sW1[(long)(EMBD + k) * HID + col];
        a += __shfl_xor(a, 1);
        if (half == 0) qcb[col] = a + sb1[col];
        return;
    }
    // W fragments: thread = (chunk c, tile, lane); 20 blocks x 256 = 5120
    int i = (b - hblocks - 1) * 256 + t;
    int c = i >> 8;
    int rest = i & 255;
    int tile = rest >> 6;
    int l = rest & 63;
    int col = tile * 32 + (l & 31);
    int kbase = c * 16 + (l >> 5) * 8;
    unsigned int hw[8], lw[8];
#pragma unroll
    for (int j = 0; j < 8; ++j) {
        int k = kbase + j;
        unsigned int hi = 0, lo = 0;
        if (k < EMBD) {
            float f = sW1[(long)k * HID + col];
            unsigned int u = __float_as_uint(f);
            hi = u >> 16;
            float r = __uint_as_float(u & 0xffff0000u);
            lo = __float_as_uint(f - r) >> 16;
        }
        hw[j] = hi; lw[j] = lo;
    }
    long fo = ((long)(c * 4 + tile) * 64 + l) * 8;
    *(u32x4*)&wfH[fo] = (u32x4){hw[0] | (hw[1] << 16), hw[2] | (hw[3] << 16),
                                hw[4] | (hw[5] << 16), hw[6] | (hw[7] << 16)};
    *(u32x4*)&wfL[fo] = (u32x4){lw[0] | (lw[1] << 16), lw[2] | (lw[3] << 16),
                                lw[4] | (lw[5] << 16), lw[6] | (lw[7] << 16)};
}

// ---------- compact ids with count >= CMIN ----------
__global__ void k_compact(const int* __restrict__ counts, int* __restrict__ cand,
                          int* __restrict__ ccnt, int* __restrict__ ncand) {
    int i = blockIdx.x * blockDim.x + threadIdx.x;
    if (i < VOCABN) {
        int c = counts[i];
        if (c >= CMIN) {
            int p = atomicAdd(ncand, 1);
            if (p < WCAND) { cand[p] = i; ccnt[p] = c; }
        }
    }
}

// ---------- barrier-free 1-wave scorer: 32 rows, 128 cols, bf16x3 MFMA ----------
// A/B frag: row|col = lane&31, k = (lane>>5)*8 + j.  C/D: col=lane&31,
// row=(r&3)+8*(r>>2)+4*(lane>>5).
__global__ __launch_bounds__(64) void k_score(
        const float* __restrict__ emb,
        const unsigned short* __restrict__ wfH,
        const unsigned short* __restrict__ wfL,
        const float* __restrict__ qcb,
        const float* __restrict__ sW2,
        const float* __restrict__ sb2,
        const int* __restrict__ counts,
        const int* __restrict__ cand,
        const int* __restrict__ ccnt,
        const int* __restrict__ ncand_p,
        const int* __restrict__ flagp,
        float* __restrict__ taw, int* __restrict__ tai) {
    if (flagp && *flagp != 0) return;        // fallback early-exit when pruning valid
    const int lane = threadIdx.x;
    const int blk = blockIdx.x;
    const int ncand = cand ? *ncand_p : VOCABN;
    const int base = blk * 32;
    if (base >= ncand) return;

    const int lrow = lane & 31;
    const int khalf = lane >> 5;

    int ri = base + lrow;
    int rc = ri < ncand ? ri : ncand - 1;
    const long row = cand ? (long)cand[rc] : (long)rc;
    const float* ebase = emb + row * EMBD;

    f32x16 acc[4];
#pragma unroll
    for (int t = 0; t < 4; ++t)
#pragma unroll
        for (int r = 0; r < 16; ++r) acc[t][r] = 0.f;

    f32x4 e0[3], e1[3];
    u32x4 wh[3][4], wl[3][4];
    const f32x4 zf4 = (f32x4){0.f, 0.f, 0.f, 0.f};

#define LOADC(NN, S)                                                         \
    { int nn_ = (NN);                                                        \
      if (nn_ < NCH) {                                                       \
          int k0_ = nn_ * 16 + khalf * 8;                                    \
          e0[S] = (k0_ + 4 <= EMBD) ? *(const f32x4*)(ebase + k0_) : zf4;    \
          e1[S] = (k0_ + 8 <= EMBD) ? *(const f32x4*)(ebase + k0_ + 4) : zf4;\
          _Pragma("unroll")                                                  \
          for (int t_ = 0; t_ < 4; ++t_) {                                   \
              long fo_ = ((long)(nn_ * 4 + t_) * 64 + lane) * 8;             \
              wh[S][t_] = *(const u32x4*)&wfH[fo_];                          \
              wl[S][t_] = *(const u32x4*)&wfL[fo_];                          \
          } } }

#define COMP(CC, S)                                                          \
    { if ((CC) < NCH) {                                                      \
          union { bf16x8 v; u32x4 u; } eh_, el_;                             \
          split8(e0[S], e1[S], &eh_.u, &el_.u);                              \
          _Pragma("unroll")                                                  \
          for (int t_ = 0; t_ < 4; ++t_) {                                   \
              union { bf16x8 v; u32x4 u; } bh_, bl_;                         \
              bh_.u = wh[S][t_]; bl_.u = wl[S][t_];                          \
              acc[t_] = __builtin_amdgcn_mfma_f32_32x32x16_bf16(eh_.v, bh_.v, acc[t_], 0, 0, 0); \
              acc[t_] = __builtin_amdgcn_mfma_f32_32x32x16_bf16(eh_.v, bl_.v, acc[t_], 0, 0, 0); \
              acc[t_] = __builtin_amdgcn_mfma_f32_32x32x16_bf16(el_.v, bh_.v, acc[t_], 0, 0, 0); \
          } } }

    LOADC(0, 0) LOADC(1, 1) LOADC(2, 2)
    for (int g = 0; g < 7; ++g) {
        int c = g * 3;
        COMP(c + 0, 0) LOADC(c + 3, 0)
        COMP(c + 1, 1) LOADC(c + 4, 1)
        COMP(c + 2, 2) LOADC(c + 5, 2)
    }
#undef LOADC
#undef COMP

    // epilogue: relu + W2 dot + 32-lane col reduce
    float qv[4], w2v[4];
#pragma unroll
    for (int t = 0; t < 4; ++t) {
        qv[t] = qcb[t * 32 + lrow];
        w2v[t] = sW2[t * 32 + lrow];
    }
    __shared__ float pv[32];
    float pr[16];
#pragma unroll
    for (int r = 0; r < 16; ++r) {
        float s = 0.f;
#pragma unroll
        for (int t = 0; t < 4; ++t) {
            float h = fmaxf(acc[t][r] + qv[t], 0.f);
            s += h * w2v[t];
        }
        s += __shfl_xor(s, 1); s += __shfl_xor(s, 2);
        s += __shfl_xor(s, 4); s += __shfl_xor(s, 8);
        s += __shfl_xor(s, 16);
        pr[r] = s;
    }
    if (lrow == 0) {
#pragma unroll
        for (int r = 0; r < 16; ++r)
            pv[(r & 3) + 8 * (r >> 2) + 4 * khalf] = pr[r];
    }
    __syncthreads();

    // weights + in-wave top-10 over 32 rows (both lane-halves duplicate)
    const float b2 = sb2[0];
    int rho = lane & 31;
    int gidx = base + rho;
    float w = -1.f; int id = 0x7fffffff;
    if (gidx < ncand) {
        int cnt = cand ? ccnt[gidx] : counts[gidx];
        id = cand ? cand[gidx] : gidx;
        w = (float)cnt / (1.f + expf(-(pv[rho] + b2)));
    }
    for (int r = 0; r < NTOP; ++r) {
        float bw = w; int bid = id;
#pragma unroll
        for (int m = 1; m < 32; m <<= 1) {
            float ow = __shfl_xor(bw, m); int oid = __shfl_xor(bid, m);
            if (ow > bw || (ow == bw && oid < bid)) { bw = ow; bid = oid; }
        }
        if (w == bw && id == bid) w = -2.f;
        if (lane == r) { taw[blk * NTOP + r] = bw; tai[blk * NTOP + r] = bid; }
    }
}

// ---------- top-k helpers ----------
__device__ __forceinline__ bool tbetter(float w1, int i1, float w2, int i2) {
    return w1 > w2 || (w1 == w2 && i1 < i2);
}

__device__ __forceinline__ void lds_insert(float* mw, int* mid, int t, float w, int id) {
    const int b = t * NTOP;
    if (!tbetter(w, id, mw[b + NTOP - 1], mid[b + NTOP - 1])) return;
    int p = NTOP - 1;
    while (p > 0 && tbetter(w, id, mw[b + p - 1], mid[b + p - 1])) {
        mw[b + p] = mw[b + p - 1]; mid[b + p] = mid[b + p - 1]; --p;
    }
    mw[b + p] = w; mid[b + p] = id;
}

// ---------- merge candidate blocks' top-10; set validity flag ----------
__global__ __launch_bounds__(256) void k_merge(const float* __restrict__ taw,
                                               const int* __restrict__ tai,
                                               const int* __restrict__ ncand_p,
                                               float* __restrict__ gtw, int* __restrict__ gti,
                                               int* __restrict__ flagp) {
    __shared__ float mw[256 * NTOP];
    __shared__ int   mid[256 * NTOP];
    int t = threadIdx.x;
#pragma unroll
    for (int n = 0; n < NTOP; ++n) { mw[t * NTOP + n] = -1.f; mid[t * NTOP + n] = 0x7fffffff; }
    int nA = (*ncand_p + 31) / 32;
    if (nA > GRID_A) nA = GRID_A;
    for (int i = t; i < nA * NTOP; i += 256)
        lds_insert(mw, mid, t, taw[i], tai[i]);
    for (int s = 128; s > 0; s >>= 1) {
        __syncthreads();
        if (t < s) {
            const int ta = t * NTOP, tb = (t + s) * NTOP;
            float ow[NTOP]; int oid[NTOP];
            int i = 0, j = 0;
#pragma unroll
            for (int n = 0; n < NTOP; ++n) {
                float wa = mw[ta + i]; int ia = mid[ta + i];
                float wb = mw[tb + j]; int ib = mid[tb + j];
                if (tbetter(wa, ia, wb, ib)) { ow[n] = wa; oid[n] = ia; ++i; }
                else                         { ow[n] = wb; oid[n] = ib; ++j; }
            }
#pragma unroll
            for (int n = 0; n < NTOP; ++n) { mw[ta + n] = ow[n]; mid[ta + n] = oid[n]; }
        }
    }
    __syncthreads();
    if (t < NTOP) { gtw[t] = mw[t]; gti[t] = mid[t]; }
    if (t == 0) *flagp = (mw[NTOP - 1] > (float)(CMIN - 1)) ? 1 : 0;
}

// ---------- final: pick top-10 source + expansion MLP ----------
__global__ __launch_bounds__(512) void k_final(const float* __restrict__ gtw,
                                               const int* __restrict__ gti,
                                               const int* __restrict__ flagp,
                                               const float* __restrict__ tbw,
                                               const int* __restrict__ tbi,
                                               const float* __restrict__ qctx,
                                               const float* __restrict__ emb,
                                               const float* __restrict__ eW1,
                                               const float* __restrict__ eb1,
                                               const float* __restrict__ eW2,
                                               const float* __restrict__ eb2,
                                               float* __restrict__ out) {
    __shared__ float mw[512 * NTOP];
    __shared__ int   mid[512 * NTOP];
    __shared__ int   top_id[NTOP];
    __shared__ float qc[EMBD], em[EMBD], hbuf[HID];
    int t = threadIdx.x;
    int ok = *flagp;
    if (ok) {
        if (t < NTOP) {
            top_id[t] = gti[t];
            out[EMBD + t] = (float)gti[t];
            out[EMBD + NTOP + t] = gtw[t];
        }
    } else {
#pragma unroll
        for (int n = 0; n < NTOP; ++n) { mw[t * NTOP + n] = -1.f; mid[t * NTOP + n] = 0x7fffffff; }
        for (int i = t; i < GRID_F * NTOP; i += 512)
            lds_insert(mw, mid, t, tbw[i], tbi[i]);
        for (int s = 256; s > 0; s >>= 1) {
            __syncthreads();
            if (t < s) {
                const int ta = t * NTOP, tb = (t + s) * NTOP;
                float ow[NTOP]; int oid[NTOP];
                int i = 0, j = 0;
#pragma unroll
                for (int n = 0; n < NTOP; ++n) {
                    float wa = mw[ta + i]; int ia = mid[ta + i];
                    float wb = mw[tb + j]; int ib = mid[tb + j];
                    if (tbetter(wa, ia, wb, ib)) { ow[n] = wa; oid[n] = ia; ++i; }
                    else                         { ow[n] = wb; oid[n] = ib; ++j; }
                }
#pragma unroll
                for (int n = 0; n < NTOP; ++n) { mw[ta + n] = ow[n]; mid[ta + n] = oid[n]; }
            }
        }
        __syncthreads();
        if (t < NTOP) {
            top_id[t] = mid[t];
            out[EMBD + t] = (float)mid[t];
            out[EMBD + NTOP + t] = mw[t];
        }
    }
    __syncthreads();

    for (int i = t; i < EMBD; i += 512) {
        float s = 0.f;
        for (int n = 0; n < NTOP; ++n) s += emb[(long)top_id[n] * EMBD + i];
        em[i] = s * (1.0f / NTOP);
        qc[i] = qctx[i];
    }
    __syncthreads();

    {   // h = relu(feat . eW1 + eb1); 4 threads per col, K split 75
        int col = t >> 2, ks = t & 3;
        float a = 0.f;
        int k0 = ks * 75, k1 = k0 + 75;
        for (int k = k0; k < k1; ++k) {
            float q = qc[k], e = em[k];
            a += q * eW1[(long)k * HID + col];
            a += e * eW1[(long)(EMBD + k) * HID + col];
            a += (q * e) * eW1[(long)(2 * EMBD + k) * HID + col];
        }
        a += __shfl_xor(a, 1);
        a += __shfl_xor(a, 2);
        if (ks == 0) hbuf[col] = fmaxf(a + eb1[col], 0.f);
    }
    __syncthreads();

    for (int i = t; i < EMBD; i += 512) {
        float a = eb2[i];
        for (int j = 0; j < HID; ++j) a += hbuf[j] * eW2[(long)j * EMBD + i];
        out[i] = a;
    }
}

extern "C" void kernel_launch(void* const* d_in, const int* in_sizes, int n_in,
                              void* d_out, int out_size, void* d_ws, size_t ws_size,
                              hipStream_t stream) {
    const int* qterms  = (const int*)d_in[0];
    const int* fdocs   = (const int*)d_in[1];
    const float* emb   = (const float*)d_in[3];
    const float* sW1   = (const float*)d_in[4];
    const float* sb1   = (const float*)d_in[5];
    const float* sW2   = (const float*)d_in[6];
    const float* sb2   = (const float*)d_in[7];
    const float* eW1   = (const float*)d_in[8];
    const float* eb1   = (const float*)d_in[9];
    const float* eW2   = (const float*)d_in[10];
    const float* eb2   = (const float*)d_in[11];
    float* out = (float*)d_out;

    char* ws = (char*)d_ws;
    int*   counts = (int*)ws;                               // 400000
    int*   ncand  = (int*)(ws + 400000);                    // 4
    float* qctx   = (float*)(ws + 400064);                  // 1200
    float* qcb    = (float*)(ws + 401280);                  // 512
    float* gtw    = (float*)(ws + 401792);                  // 40
    int*   gti    = (int*)(ws + 401856);                    // 40
    int*   flagp  = (int*)(ws + 401920);                    // 4
    int*   cand   = (int*)(ws + 402432);                    // 174764
    int*   ccnt   = (int*)(ws + 577280);                    // 174764
    unsigned short* wfH = (unsigned short*)(ws + 752128);   // 81920
    unsigned short* wfL = (unsigned short*)(ws + 834048);   // 81920
    float* taw    = (float*)(ws + 915968);                  // GRID_A*10*4 = 54640
    int*   tai    = (int*)(ws + 970624);                    // 54640
    float* tbw    = (float*)(ws + 1025280);                 // GRID_F*10*4 = 125000
    int*   tbi    = (int*)(ws + 1150336);                   // 125000

    int nflat = in_sizes[1];
    int hblocks = (nflat + 255) / 256;     // 512

    hipMemsetAsync(ws, 0, 400064, stream);                  // counts + ncand
    k_pre<<<hblocks + 1 + NCH, 256, 0, stream>>>(qterms, fdocs, nflat, hblocks,
                                                 emb, sW1, sb1, counts, qctx, qcb, wfH, wfL);
    k_compact<<<(VOCABN + 255) / 256, 256, 0, stream>>>(counts, cand, ccnt, ncand);
    // stage A: score candidates only (count >= CMIN)
    k_score<<<GRID_A, 64, 0, stream>>>(emb, wfH, wfL, qcb, sW2, sb2,
                                       counts, cand, ccnt, ncand, (const int*)nullptr, taw, tai);
    k_merge<<<1, 256, 0, stream>>>(taw, tai, ncand, gtw, gti, flagp);
    // exactness fallback: full sweep, early-exits when pruning was valid
    k_score<<<GRID_F, 64, 0, stream>>>(emb, wfH, wfL, qcb, sW2, sb2,
                                       counts, (const int*)nullptr, (const int*)nullptr,
                                       (const int*)nullptr, flagp, tbw, tbi);
    k_final<<<1, 512, 0, stream>>>(gtw, gti, flagp, tbw, tbi,
                                   qctx, emb, eW1, eb1, eW2, eb2, out);
}